// Round 1
// baseline (312.813 us; speedup 1.0000x reference)
//
#include <hip/hip_runtime.h>
#include <hip/hip_bf16.h>
#include <math.h>

typedef __bf16 bf16_t;
typedef __bf16 bf16x8 __attribute__((ext_vector_type(8)));
typedef float f32x4 __attribute__((ext_vector_type(4)));

#define MFMA16(a, b, c) __builtin_amdgcn_mfma_f32_16x16x32_bf16((a), (b), (c), 0, 0, 0)

// ---------------------------------------------------------------------------
// Weight transpose + f32->bf16 convert: dst[n][k] = (bf16) src[k][n], 768x768
// ---------------------------------------------------------------------------
struct WPtrs {
    const float* src[7];
    bf16_t* dst[7];
};

__global__ __launch_bounds__(256) void transpose_w_kernel(WPtrs p) {
    __shared__ float t[32][33];
    const float* src = p.src[blockIdx.z];
    bf16_t* dst = p.dst[blockIdx.z];
    const int tx = threadIdx.x, ty = threadIdx.y;
    const int x = blockIdx.x * 32 + tx;   // src col
    const int y0 = blockIdx.y * 32;       // src row base
#pragma unroll
    for (int j = 0; j < 4; ++j)
        t[ty + j * 8][tx] = src[(size_t)(y0 + ty + j * 8) * 768 + x];
    __syncthreads();
    const int ox = blockIdx.y * 32 + tx;  // dst col = src row
    const int oy0 = blockIdx.x * 32;      // dst row = src col
#pragma unroll
    for (int j = 0; j < 4; ++j)
        dst[(size_t)(oy0 + ty + j * 8) * 768 + ox] = (bf16_t)t[tx][ty + j * 8];
}

// ---------------------------------------------------------------------------
// v [4096,768] bf16 (head-major cols) -> Vt [96][64][512] bf16 (d-major)
// ---------------------------------------------------------------------------
__global__ __launch_bounds__(256) void transpose_v_kernel(const bf16_t* __restrict__ vb,
                                                          bf16_t* __restrict__ Vt) {
    __shared__ bf16_t t[32][34];
    const int bh = blockIdx.z, b = bh / 12, h = bh % 12;
    const int l0 = blockIdx.x * 32, d0 = blockIdx.y * 32;
    const int tx = threadIdx.x, ty = threadIdx.y;
#pragma unroll
    for (int j = 0; j < 4; ++j)
        t[ty + j * 8][tx] = vb[(size_t)(b * 512 + l0 + ty + j * 8) * 768 + h * 64 + d0 + tx];
    __syncthreads();
#pragma unroll
    for (int j = 0; j < 4; ++j)
        Vt[((size_t)bh * 64 + d0 + ty + j * 8) * 512 + l0 + tx] = t[tx][ty + j * 8];
}

// ---------------------------------------------------------------------------
// GEMM: C[M,N] = A[M,K] @ Bt[N,K]^T  (Bt is transposed weight, bf16)
// A is f32 (converted during staging) or bf16. Epilogue: bias/relu/residual.
// Tile: BM=128, BN=64, BK=32; 4 waves; wave w -> rows [w*32, w*32+32), all 64 cols.
// ---------------------------------------------------------------------------
template <bool A_F32, bool HAS_BIAS, bool RELU, bool HAS_RES, bool OUT_BF16>
__global__ __launch_bounds__(256) void gemm_kernel(const void* __restrict__ Av,
                                                   const bf16_t* __restrict__ Bt,
                                                   const float* __restrict__ bias,
                                                   const float* __restrict__ Res,
                                                   float* __restrict__ Cf,
                                                   bf16_t* __restrict__ Cb,
                                                   int M, int N, int K) {
    __shared__ __align__(16) bf16_t As[128][40];  // pad 8 elems (16B) keeps 16B align
    __shared__ __align__(16) bf16_t Bs[64][40];
    const int tid = threadIdx.x;
    const int w = tid >> 6, l = tid & 63, l16 = l & 15, lk = l >> 4;
    const int row0 = blockIdx.y * 128, col0 = blockIdx.x * 64;
    const int r = tid >> 2, c8 = (tid & 3) * 8;
    f32x4 acc[2][4] = {};

    for (int k0 = 0; k0 < K; k0 += 32) {
        __syncthreads();
        if constexpr (A_F32) {
            const float* A = (const float*)Av;
#pragma unroll
            for (int j = 0; j < 2; ++j) {
                const int rr = r + j * 64;
                const float* s = A + (size_t)(row0 + rr) * K + k0 + c8;
                const float4 u = *(const float4*)s;
                const float4 v = *(const float4*)(s + 4);
                bf16x8 o;
                o[0] = (bf16_t)u.x; o[1] = (bf16_t)u.y; o[2] = (bf16_t)u.z; o[3] = (bf16_t)u.w;
                o[4] = (bf16_t)v.x; o[5] = (bf16_t)v.y; o[6] = (bf16_t)v.z; o[7] = (bf16_t)v.w;
                *(bf16x8*)&As[rr][c8] = o;
            }
        } else {
            const bf16_t* A = (const bf16_t*)Av;
#pragma unroll
            for (int j = 0; j < 2; ++j) {
                const int rr = r + j * 64;
                *(bf16x8*)&As[rr][c8] = *(const bf16x8*)(A + (size_t)(row0 + rr) * K + k0 + c8);
            }
        }
        *(bf16x8*)&Bs[r][c8] = *(const bf16x8*)(Bt + (size_t)(col0 + r) * K + k0 + c8);
        __syncthreads();

        const bf16x8 af0 = *(const bf16x8*)&As[w * 32 + l16][lk * 8];
        const bf16x8 af1 = *(const bf16x8*)&As[w * 32 + 16 + l16][lk * 8];
#pragma unroll
        for (int nt = 0; nt < 4; ++nt) {
            const bf16x8 bv = *(const bf16x8*)&Bs[nt * 16 + l16][lk * 8];
            acc[0][nt] = MFMA16(af0, bv, acc[0][nt]);
            acc[1][nt] = MFMA16(af1, bv, acc[1][nt]);
        }
    }

#pragma unroll
    for (int mt = 0; mt < 2; ++mt)
#pragma unroll
        for (int nt = 0; nt < 4; ++nt)
#pragma unroll
            for (int i = 0; i < 4; ++i) {
                const int row = row0 + w * 32 + mt * 16 + lk * 4 + i;
                const int col = col0 + nt * 16 + l16;
                float val = acc[mt][nt][i];
                if constexpr (HAS_BIAS) val += bias[col];
                if constexpr (RELU) val = fmaxf(val, 0.0f);
                if constexpr (HAS_RES) val += Res[(size_t)row * N + col];
                const size_t o = (size_t)row * N + col;
                if constexpr (OUT_BF16) Cb[o] = (bf16_t)val;
                else Cf[o] = val;
            }
}

// ---------------------------------------------------------------------------
// Fused dual-softmax attention. One block = (b, h, 32 q-rows). 4 waves.
// Wave w owns key-slice [w*128, w*128+128).
// ---------------------------------------------------------------------------
__global__ __launch_bounds__(256) void attn_kernel(const bf16_t* __restrict__ qb,
                                                   const bf16_t* __restrict__ kb,
                                                   const bf16_t* __restrict__ Vt,
                                                   const float* __restrict__ Wpos,
                                                   const float* __restrict__ Wneg,
                                                   bf16_t* __restrict__ Vpb,
                                                   bf16_t* __restrict__ Vnb) {
    __shared__ __align__(16) bf16_t Ps[32][520];  // pad to 520 (1040B rows, 16B-mult)
    __shared__ __align__(16) bf16_t Ns[32][520];
    __shared__ float mxp[4][32], mxn[4][32], smp[4][32], smn[4][32];
    const int tid = threadIdx.x, w = tid >> 6, l = tid & 63, l16 = l & 15, lk = l >> 4;
    const int qt = blockIdx.x, bh = blockIdx.y, b = bh / 12, h = bh % 12;
    const int q0 = qt * 32;

    // --- phase 1: S = q @ k^T / temp, wave's 128-col slice, 32 rows ---
    f32x4 sacc[2][8] = {};
    {
        const size_t qbase = ((size_t)(b * 512 + q0)) * 768 + h * 64;
        const size_t kbase = ((size_t)(b * 512 + w * 128)) * 768 + h * 64;
#pragma unroll
        for (int ks = 0; ks < 2; ++ks) {
            const bf16x8 a0 = *(const bf16x8*)(qb + qbase + (size_t)l16 * 768 + ks * 32 + lk * 8);
            const bf16x8 a1 = *(const bf16x8*)(qb + qbase + (size_t)(16 + l16) * 768 + ks * 32 + lk * 8);
#pragma unroll
            for (int nt = 0; nt < 8; ++nt) {
                const bf16x8 bv =
                    *(const bf16x8*)(kb + kbase + (size_t)(nt * 16 + l16) * 768 + ks * 32 + lk * 8);
                sacc[0][nt] = MFMA16(a0, bv, sacc[0][nt]);
                sacc[1][nt] = MFMA16(a1, bv, sacc[1][nt]);
            }
        }
    }
    const float invt = 1.0f / (8.0f + 1e-6f);
    float dp[8], dn[8];
#pragma unroll
    for (int nt = 0; nt < 8; ++nt) {
        const int col = w * 128 + nt * 16 + l16;
        dp[nt] = Wpos[(size_t)col * 513];
        dn[nt] = Wneg[(size_t)col * 513];
    }

    // --- phase 2: row maxes (pos & neg logits) ---
    float mp[8], mn[8];  // [mt*4+i]
#pragma unroll
    for (int mt = 0; mt < 2; ++mt)
#pragma unroll
        for (int i = 0; i < 4; ++i) {
            float a = -1e30f, c = -1e30f;
#pragma unroll
            for (int nt = 0; nt < 8; ++nt) {
                const float s = sacc[mt][nt][i] * invt;
                a = fmaxf(a, s * dp[nt]);
                c = fmaxf(c, -s * dn[nt]);
            }
            mp[mt * 4 + i] = a;
            mn[mt * 4 + i] = c;
        }
#pragma unroll
    for (int off = 1; off < 16; off <<= 1)
#pragma unroll
        for (int e = 0; e < 8; ++e) {
            mp[e] = fmaxf(mp[e], __shfl_xor(mp[e], off, 64));
            mn[e] = fmaxf(mn[e], __shfl_xor(mn[e], off, 64));
        }
    if (l16 == 0) {
#pragma unroll
        for (int mt = 0; mt < 2; ++mt)
#pragma unroll
            for (int i = 0; i < 4; ++i) {
                mxp[w][mt * 16 + lk * 4 + i] = mp[mt * 4 + i];
                mxn[w][mt * 16 + lk * 4 + i] = mn[mt * 4 + i];
            }
    }
    __syncthreads();
    float gmp[8], gmn[8];
#pragma unroll
    for (int mt = 0; mt < 2; ++mt)
#pragma unroll
        for (int i = 0; i < 4; ++i) {
            const int rrow = mt * 16 + lk * 4 + i;
            gmp[mt * 4 + i] = fmaxf(fmaxf(mxp[0][rrow], mxp[1][rrow]), fmaxf(mxp[2][rrow], mxp[3][rrow]));
            gmn[mt * 4 + i] = fmaxf(fmaxf(mxn[0][rrow], mxn[1][rrow]), fmaxf(mxn[2][rrow], mxn[3][rrow]));
        }

    // --- phase 3: exp, write unnormalized P (bf16) to LDS, row sums ---
    float sp[8] = {0, 0, 0, 0, 0, 0, 0, 0}, sn2[8] = {0, 0, 0, 0, 0, 0, 0, 0};
#pragma unroll
    for (int mt = 0; mt < 2; ++mt)
#pragma unroll
        for (int nt = 0; nt < 8; ++nt)
#pragma unroll
            for (int i = 0; i < 4; ++i) {
                const int rrow = mt * 16 + lk * 4 + i;
                const int col = w * 128 + nt * 16 + l16;
                const float s = sacc[mt][nt][i] * invt;
                const float ep = expf(s * dp[nt] - gmp[mt * 4 + i]);
                const float en = expf(-s * dn[nt] - gmn[mt * 4 + i]);
                Ps[rrow][col] = (bf16_t)ep;
                Ns[rrow][col] = (bf16_t)en;
                sp[mt * 4 + i] += ep;
                sn2[mt * 4 + i] += en;
            }
#pragma unroll
    for (int off = 1; off < 16; off <<= 1)
#pragma unroll
        for (int e = 0; e < 8; ++e) {
            sp[e] += __shfl_xor(sp[e], off, 64);
            sn2[e] += __shfl_xor(sn2[e], off, 64);
        }
    if (l16 == 0) {
#pragma unroll
        for (int mt = 0; mt < 2; ++mt)
#pragma unroll
            for (int i = 0; i < 4; ++i) {
                smp[w][mt * 16 + lk * 4 + i] = sp[mt * 4 + i];
                smn[w][mt * 16 + lk * 4 + i] = sn2[mt * 4 + i];
            }
    }
    __syncthreads();

    // --- phase 4: PV over this wave's k-slice (partials) ---
    f32x4 pacc[2][4] = {}, nacc[2][4] = {};
    const size_t vtb = (size_t)bh * 64 * 512;
#pragma unroll
    for (int kt = 0; kt < 4; ++kt) {
        const int kc = w * 128 + kt * 32 + lk * 8;
        const bf16x8 ap0 = *(const bf16x8*)&Ps[l16][kc];
        const bf16x8 ap1 = *(const bf16x8*)&Ps[16 + l16][kc];
        const bf16x8 an0 = *(const bf16x8*)&Ns[l16][kc];
        const bf16x8 an1 = *(const bf16x8*)&Ns[16 + l16][kc];
#pragma unroll
        for (int nd = 0; nd < 4; ++nd) {
            const bf16x8 bv = *(const bf16x8*)(Vt + vtb + (size_t)(nd * 16 + l16) * 512 + kc);
            pacc[0][nd] = MFMA16(ap0, bv, pacc[0][nd]);
            pacc[1][nd] = MFMA16(ap1, bv, pacc[1][nd]);
            nacc[0][nd] = MFMA16(an0, bv, nacc[0][nd]);
            nacc[1][nd] = MFMA16(an1, bv, nacc[1][nd]);
        }
    }
    __syncthreads();

    // --- phase 5: cross-wave reduce (reuse P LDS), normalize, store bf16 ---
    float* Rp = (float*)&Ps[0][0];
    float* Rn = (float*)&Ns[0][0];
#pragma unroll
    for (int mt = 0; mt < 2; ++mt)
#pragma unroll
        for (int nd = 0; nd < 4; ++nd)
#pragma unroll
            for (int i = 0; i < 4; ++i) {
                const int rrow = mt * 16 + lk * 4 + i, col = nd * 16 + l16;
                Rp[w * 2048 + rrow * 64 + col] = pacc[mt][nd][i];
                Rn[w * 2048 + rrow * 64 + col] = nacc[mt][nd][i];
            }
    __syncthreads();
    for (int e = tid; e < 2048; e += 256) {
        const int rrow = e >> 6, col = e & 63;
        const float stp = smp[0][rrow] + smp[1][rrow] + smp[2][rrow] + smp[3][rrow];
        const float stn = smn[0][rrow] + smn[1][rrow] + smn[2][rrow] + smn[3][rrow];
        const float vp = (Rp[e] + Rp[2048 + e] + Rp[4096 + e] + Rp[6144 + e]) / stp;
        const float vn = -(Rn[e] + Rn[2048 + e] + Rn[4096 + e] + Rn[6144 + e]) / stn;
        const size_t o = ((size_t)(b * 512 + q0 + rrow)) * 768 + h * 64 + col;
        Vpb[o] = (bf16_t)vp;
        Vnb[o] = (bf16_t)vn;
    }
}

// ---------------------------------------------------------------------------
extern "C" void kernel_launch(void* const* d_in, const int* in_sizes, int n_in,
                              void* d_out, int out_size, void* d_ws, size_t ws_size,
                              hipStream_t stream) {
    const float* Q = (const float*)d_in[0];
    const float* K = (const float*)d_in[1];
    const float* V = (const float*)d_in[2];
    const float* W_q = (const float*)d_in[3];
    const float* W_k = (const float*)d_in[4];
    const float* W_v = (const float*)d_in[5];
    const float* Wpos = (const float*)d_in[6];
    const float* Wneg = (const float*)d_in[7];
    const float* W_o = (const float*)d_in[8];
    const float* W_o2 = (const float*)d_in[9];
    const float* w1 = (const float*)d_in[10];
    const float* b1 = (const float*)d_in[11];
    const float* w2 = (const float*)d_in[12];
    const float* b2 = (const float*)d_in[13];
    float* out = (float*)d_out;

    char* ws = (char*)d_ws;
    const size_t act_b = (size_t)4096 * 768 * 2;  // bf16 [4096,768]
    const size_t act_f = (size_t)4096 * 768 * 4;  // f32  [4096,768]
    const size_t wt_b = (size_t)768 * 768 * 2;    // bf16 [768,768]
    size_t off = 0;
    bf16_t* qb = (bf16_t*)(ws + off); off += act_b;
    bf16_t* kb = (bf16_t*)(ws + off); off += act_b;
    bf16_t* vb = (bf16_t*)(ws + off); off += act_b;
    bf16_t* Vt = (bf16_t*)(ws + off); off += act_b;
    bf16_t* Vpb = (bf16_t*)(ws + off); off += act_b;
    bf16_t* Vnb = (bf16_t*)(ws + off); off += act_b;
    bf16_t* Hp = (bf16_t*)(ws + off); off += act_b;
    bf16_t* Hn = (bf16_t*)(ws + off); off += act_b;
    float* Xp = (float*)(ws + off); off += act_f;
    float* Xn = (float*)(ws + off); off += act_f;
    bf16_t* Wt[7];
    for (int i = 0; i < 7; ++i) { Wt[i] = (bf16_t*)(ws + off); off += wt_b; }

    WPtrs wp;
    wp.src[0] = W_q;  wp.src[1] = W_k;  wp.src[2] = W_v;
    wp.src[3] = W_o;  wp.src[4] = W_o2; wp.src[5] = w1; wp.src[6] = w2;
    for (int i = 0; i < 7; ++i) wp.dst[i] = Wt[i];
    transpose_w_kernel<<<dim3(24, 24, 7), dim3(32, 8), 0, stream>>>(wp);

    const dim3 gg(12, 32), gb(256);
    // projections: q, k, v (A = f32 input, out bf16)
    gemm_kernel<true, false, false, false, true><<<gg, gb, 0, stream>>>(Q, Wt[0], nullptr, nullptr, nullptr, qb, 4096, 768, 768);
    gemm_kernel<true, false, false, false, true><<<gg, gb, 0, stream>>>(K, Wt[1], nullptr, nullptr, nullptr, kb, 4096, 768, 768);
    gemm_kernel<true, false, false, false, true><<<gg, gb, 0, stream>>>(V, Wt[2], nullptr, nullptr, nullptr, vb, 4096, 768, 768);
    transpose_v_kernel<<<dim3(16, 2, 96), dim3(32, 8), 0, stream>>>(vb, Vt);
    attn_kernel<<<dim3(16, 96), gb, 0, stream>>>(qb, kb, Vt, Wpos, Wneg, Vpb, Vnb);
    // out projections + residual Q -> X (f32)
    gemm_kernel<false, false, false, true, false><<<gg, gb, 0, stream>>>(Vpb, Wt[3], nullptr, Q, Xp, nullptr, 4096, 768, 768);
    gemm_kernel<false, false, false, true, false><<<gg, gb, 0, stream>>>(Vnb, Wt[4], nullptr, Q, Xn, nullptr, 4096, 768, 768);
    // FFN1: relu(X @ w1 + b1) -> H (bf16); A is f32
    gemm_kernel<true, true, true, false, true><<<gg, gb, 0, stream>>>(Xp, Wt[5], b1, nullptr, nullptr, Hp, 4096, 768, 768);
    gemm_kernel<true, true, true, false, true><<<gg, gb, 0, stream>>>(Xn, Wt[5], b1, nullptr, nullptr, Hn, 4096, 768, 768);
    // FFN2: H @ w2 + b2 + X -> out (f32)
    gemm_kernel<false, true, false, true, false><<<gg, gb, 0, stream>>>(Hp, Wt[6], b2, Xp, out, nullptr, 4096, 768, 768);
    gemm_kernel<false, true, false, true, false><<<gg, gb, 0, stream>>>(Hn, Wt[6], b2, Xn, out + (size_t)4096 * 768, nullptr, 4096, 768, 768);
}

// Round 2
// 190.995 us; speedup vs baseline: 1.6378x; 1.6378x over previous
//
#include <hip/hip_runtime.h>
#include <hip/hip_bf16.h>
#include <math.h>

typedef __bf16 bf16_t;
typedef __bf16 bf16x8 __attribute__((ext_vector_type(8)));
typedef float f32x4 __attribute__((ext_vector_type(4)));

#define MFMA16(a, b, c) __builtin_amdgcn_mfma_f32_16x16x32_bf16((a), (b), (c), 0, 0, 0)
#define EXP2F(x) __builtin_amdgcn_exp2f(x)

__device__ __forceinline__ void gll16(const void* g, void* lds) {
    __builtin_amdgcn_global_load_lds((const __attribute__((address_space(1))) void*)g,
                                     (__attribute__((address_space(3))) void*)lds, 16, 0, 0);
}

// ---------------------------------------------------------------------------
// f32 -> bf16 convert (vectorized): 3 tensors of 4096*768
// ---------------------------------------------------------------------------
struct CvtPtrs {
    const float* src[3];
    bf16_t* dst[3];
};

__global__ __launch_bounds__(256) void convert_kernel(CvtPtrs p, int n8) {
    const float* src = p.src[blockIdx.y];
    bf16_t* dst = p.dst[blockIdx.y];
    const int i = blockIdx.x * 256 + threadIdx.x;
    if (i < n8) {
        const float4 u = ((const float4*)src)[i * 2];
        const float4 v = ((const float4*)src)[i * 2 + 1];
        bf16x8 o;
        o[0] = (bf16_t)u.x; o[1] = (bf16_t)u.y; o[2] = (bf16_t)u.z; o[3] = (bf16_t)u.w;
        o[4] = (bf16_t)v.x; o[5] = (bf16_t)v.y; o[6] = (bf16_t)v.z; o[7] = (bf16_t)v.w;
        ((bf16x8*)dst)[i] = o;
    }
}

// ---------------------------------------------------------------------------
// Weight transpose + f32->bf16 convert: dst[n][k] = (bf16) src[k][n], 768x768
// ---------------------------------------------------------------------------
struct WPtrs {
    const float* src[7];
    bf16_t* dst[7];
};

__global__ __launch_bounds__(256) void transpose_w_kernel(WPtrs p) {
    __shared__ float t[32][33];
    const float* src = p.src[blockIdx.z];
    bf16_t* dst = p.dst[blockIdx.z];
    const int tx = threadIdx.x, ty = threadIdx.y;
    const int x = blockIdx.x * 32 + tx;
    const int y0 = blockIdx.y * 32;
#pragma unroll
    for (int j = 0; j < 4; ++j)
        t[ty + j * 8][tx] = src[(size_t)(y0 + ty + j * 8) * 768 + x];
    __syncthreads();
    const int ox = blockIdx.y * 32 + tx;
    const int oy0 = blockIdx.x * 32;
#pragma unroll
    for (int j = 0; j < 4; ++j)
        dst[(size_t)(oy0 + ty + j * 8) * 768 + ox] = (bf16_t)t[tx][ty + j * 8];
}

// ---------------------------------------------------------------------------
// v [4096,768] bf16 (head-major cols) -> Vt [96][64][512] bf16 (d-major)
// ---------------------------------------------------------------------------
__global__ __launch_bounds__(256) void transpose_v_kernel(const bf16_t* __restrict__ vb,
                                                          bf16_t* __restrict__ Vt) {
    __shared__ bf16_t t[32][34];
    const int bh = blockIdx.z, b = bh / 12, h = bh % 12;
    const int l0 = blockIdx.x * 32, d0 = blockIdx.y * 32;
    const int tx = threadIdx.x, ty = threadIdx.y;
#pragma unroll
    for (int j = 0; j < 4; ++j)
        t[ty + j * 8][tx] = vb[(size_t)(b * 512 + l0 + ty + j * 8) * 768 + h * 64 + d0 + tx];
    __syncthreads();
#pragma unroll
    for (int j = 0; j < 4; ++j)
        Vt[((size_t)bh * 64 + d0 + ty + j * 8) * 512 + l0 + tx] = t[tx][ty + j * 8];
}

// ---------------------------------------------------------------------------
// GEMM: C[M,N] = A[M,K] @ Bt[N,K]^T, A and Bt bf16, staged via global_load_lds
// BM=128, BN=64, BK=64. LDS linear rows of 128B with XOR-chunk swizzle applied
// to the pre-swizzled GLOBAL source and to the ds_read (rule 21 involution).
// 4 waves; wave w computes rows [w*32, w*32+32) x 64 cols.
// Batched over blockIdx.z via pointer arrays.
// OUTMODE: 0 = f32, 1 = bf16, 2 = dual (f32 + bf16)
// ---------------------------------------------------------------------------
struct GemmB {
    const bf16_t* A[3];
    const bf16_t* Bt[3];
    const float* bias;
    const float* Res[3];
    float* Cf[3];
    bf16_t* Cb[3];
};

template <bool HAS_BIAS, bool RELU, bool HAS_RES, int OUTMODE>
__global__ __launch_bounds__(256) void gemm2(GemmB p, int M, int K, int N) {
    __shared__ __align__(16) bf16_t As[128 * 64];  // 16 KB, rows of 128 B
    __shared__ __align__(16) bf16_t Bs[64 * 64];   // 8 KB
    const int z = blockIdx.z;
    const bf16_t* __restrict__ A = p.A[z];
    const bf16_t* __restrict__ Bt = p.Bt[z];
    const int tid = threadIdx.x, w = tid >> 6, l = tid & 63, l16 = l & 15, lk = l >> 4;
    const int row0 = blockIdx.y * 128, col0 = blockIdx.x * 64;
    f32x4 acc[2][4] = {};

    // staging source offsets (element offsets, add k0 later); XOR pre-swizzle
    const int lofs = w * 1024 + l * 16;  // byte offset within a 4KB issue chunk
    size_t aEl[4];
    size_t bEl[2];
#pragma unroll
    for (int i = 0; i < 4; ++i) {
        const int off = i * 4096 + lofs;
        const int row = off >> 7;
        const int c = ((off >> 4) & 7) ^ (row & 7);
        aEl[i] = (size_t)(row0 + row) * K + c * 8;
    }
#pragma unroll
    for (int i = 0; i < 2; ++i) {
        const int off = i * 4096 + lofs;
        const int row = off >> 7;
        const int c = ((off >> 4) & 7) ^ (row & 7);
        bEl[i] = (size_t)(col0 + row) * K + c * 8;
    }

    for (int k0 = 0; k0 < K; k0 += 64) {
        __syncthreads();
#pragma unroll
        for (int i = 0; i < 4; ++i)
            gll16(A + aEl[i] + k0, (char*)As + i * 4096 + w * 1024);
#pragma unroll
        for (int i = 0; i < 2; ++i)
            gll16(Bt + bEl[i] + k0, (char*)Bs + i * 4096 + w * 1024);
        __syncthreads();

#pragma unroll
        for (int kk = 0; kk < 2; ++kk) {
            const int ar0 = w * 32 + l16, ar1 = w * 32 + 16 + l16;
            const bf16x8 a0 = *(const bf16x8*)((const char*)As + ar0 * 128 +
                                               (((kk * 4 + lk) ^ (ar0 & 7)) << 4));
            const bf16x8 a1 = *(const bf16x8*)((const char*)As + ar1 * 128 +
                                               (((kk * 4 + lk) ^ (ar1 & 7)) << 4));
#pragma unroll
            for (int nt = 0; nt < 4; ++nt) {
                const int br = nt * 16 + l16;
                const bf16x8 bv = *(const bf16x8*)((const char*)Bs + br * 128 +
                                                   (((kk * 4 + lk) ^ (br & 7)) << 4));
                acc[0][nt] = MFMA16(a0, bv, acc[0][nt]);
                acc[1][nt] = MFMA16(a1, bv, acc[1][nt]);
            }
        }
    }

#pragma unroll
    for (int mt = 0; mt < 2; ++mt)
#pragma unroll
        for (int nt = 0; nt < 4; ++nt)
#pragma unroll
            for (int i = 0; i < 4; ++i) {
                const int row = row0 + w * 32 + mt * 16 + lk * 4 + i;
                const int col = col0 + nt * 16 + l16;
                float val = acc[mt][nt][i];
                if constexpr (HAS_BIAS) val += p.bias[col];
                if constexpr (RELU) val = fmaxf(val, 0.0f);
                if constexpr (HAS_RES) val += p.Res[z][(size_t)row * N + col];
                const size_t o = (size_t)row * N + col;
                if constexpr (OUTMODE == 0) {
                    p.Cf[z][o] = val;
                } else if constexpr (OUTMODE == 1) {
                    p.Cb[z][o] = (bf16_t)val;
                } else {
                    p.Cf[z][o] = val;
                    p.Cb[z][o] = (bf16_t)val;
                }
            }
}

// ---------------------------------------------------------------------------
// Fused dual-softmax attention. One block = (b, h, 16 q-rows). 4 waves.
// Wave w owns key-slice [w*128, w*128+128). exp2-based softmax (scale folded).
// ---------------------------------------------------------------------------
__global__ __launch_bounds__(256) void attn_kernel(const bf16_t* __restrict__ qb,
                                                   const bf16_t* __restrict__ kb,
                                                   const bf16_t* __restrict__ Vt,
                                                   const float* __restrict__ Wpos,
                                                   const float* __restrict__ Wneg,
                                                   bf16_t* __restrict__ Vpb,
                                                   bf16_t* __restrict__ Vnb) {
    __shared__ __align__(16) bf16_t Ps[16][520];  // 16640 B (row = 1040 B)
    __shared__ __align__(16) bf16_t Ns[16][520];
    __shared__ float mxp[4][16], mxn[4][16], smp[4][16], smn[4][16];
    const int tid = threadIdx.x, w = tid >> 6, l = tid & 63, l16 = l & 15, lk = l >> 4;
    const int qt = blockIdx.x, bh = blockIdx.y, b = bh / 12, h = bh % 12;
    const int q0 = qt * 16;

    // --- phase 1: S = q @ k^T, wave's 128-key slice, 16 q-rows ---
    f32x4 sacc[8] = {};
    {
        const size_t qbase = ((size_t)(b * 512 + q0)) * 768 + h * 64;
        const size_t kbase = ((size_t)(b * 512 + w * 128)) * 768 + h * 64;
#pragma unroll
        for (int ks = 0; ks < 2; ++ks) {
            const bf16x8 a0 = *(const bf16x8*)(qb + qbase + (size_t)l16 * 768 + ks * 32 + lk * 8);
#pragma unroll
            for (int nt = 0; nt < 8; ++nt) {
                const bf16x8 bv =
                    *(const bf16x8*)(kb + kbase + (size_t)(nt * 16 + l16) * 768 + ks * 32 + lk * 8);
                sacc[nt] = MFMA16(a0, bv, sacc[nt]);
            }
        }
    }
    // diag scalars with 1/temp and log2(e) folded in
    const float SC = 1.4426950408889634f / (8.0f + 1e-6f);
    float dp[8], dn[8];
#pragma unroll
    for (int nt = 0; nt < 8; ++nt) {
        const int col = w * 128 + nt * 16 + l16;
        dp[nt] = Wpos[(size_t)col * 513] * SC;
        dn[nt] = Wneg[(size_t)col * 513] * SC;
    }

    // --- phase 2: row maxes over this wave's slice, then cross-wave ---
    float mp[4] = {-1e30f, -1e30f, -1e30f, -1e30f};
    float mn[4] = {-1e30f, -1e30f, -1e30f, -1e30f};
#pragma unroll
    for (int nt = 0; nt < 8; ++nt)
#pragma unroll
        for (int i = 0; i < 4; ++i) {
            const float s = sacc[nt][i];
            mp[i] = fmaxf(mp[i], s * dp[nt]);
            mn[i] = fmaxf(mn[i], -s * dn[nt]);
        }
#pragma unroll
    for (int off = 1; off < 16; off <<= 1)
#pragma unroll
        for (int e = 0; e < 4; ++e) {
            mp[e] = fmaxf(mp[e], __shfl_xor(mp[e], off, 64));
            mn[e] = fmaxf(mn[e], __shfl_xor(mn[e], off, 64));
        }
    if (l16 == 0) {
#pragma unroll
        for (int i = 0; i < 4; ++i) {
            mxp[w][lk * 4 + i] = mp[i];
            mxn[w][lk * 4 + i] = mn[i];
        }
    }
    __syncthreads();
    float gmp[4], gmn[4];
#pragma unroll
    for (int i = 0; i < 4; ++i) {
        const int r = lk * 4 + i;
        gmp[i] = fmaxf(fmaxf(mxp[0][r], mxp[1][r]), fmaxf(mxp[2][r], mxp[3][r]));
        gmn[i] = fmaxf(fmaxf(mxn[0][r], mxn[1][r]), fmaxf(mxn[2][r], mxn[3][r]));
    }

    // --- phase 3: exp2, write unnormalized P/N (bf16) to LDS, row sums ---
    float sp[4] = {0, 0, 0, 0}, sn[4] = {0, 0, 0, 0};
#pragma unroll
    for (int nt = 0; nt < 8; ++nt) {
        const int col = w * 128 + nt * 16 + l16;
#pragma unroll
        for (int i = 0; i < 4; ++i) {
            const float s = sacc[nt][i];
            const float ep = EXP2F(s * dp[nt] - gmp[i]);
            const float en = EXP2F(-s * dn[nt] - gmn[i]);
            Ps[lk * 4 + i][col] = (bf16_t)ep;
            Ns[lk * 4 + i][col] = (bf16_t)en;
            sp[i] += ep;
            sn[i] += en;
        }
    }
#pragma unroll
    for (int off = 1; off < 16; off <<= 1)
#pragma unroll
        for (int e = 0; e < 4; ++e) {
            sp[e] += __shfl_xor(sp[e], off, 64);
            sn[e] += __shfl_xor(sn[e], off, 64);
        }
    if (l16 == 0) {
#pragma unroll
        for (int i = 0; i < 4; ++i) {
            smp[w][lk * 4 + i] = sp[i];
            smn[w][lk * 4 + i] = sn[i];
        }
    }
    __syncthreads();

    // --- phase 4: PV partials over this wave's key-slice ---
    f32x4 pacc[4] = {}, nacc[4] = {};
    const size_t vtb = (size_t)bh * 64 * 512;
#pragma unroll
    for (int kt = 0; kt < 4; ++kt) {
        const int kc = w * 128 + kt * 32 + lk * 8;
        const bf16x8 ap = *(const bf16x8*)&Ps[l16][kc];
        const bf16x8 an = *(const bf16x8*)&Ns[l16][kc];
#pragma unroll
        for (int nd = 0; nd < 4; ++nd) {
            const bf16x8 bv = *(const bf16x8*)(Vt + vtb + (size_t)(nd * 16 + l16) * 512 + kc);
            pacc[nd] = MFMA16(ap, bv, pacc[nd]);
            nacc[nd] = MFMA16(an, bv, nacc[nd]);
        }
    }
    __syncthreads();

    // --- phase 5: cross-wave reduce via f32 scratch (reuse Ps/Ns), store ---
    float* Rp = (float*)&Ps[0][0];  // [4][16][65] = 16640 B exactly
    float* Rn = (float*)&Ns[0][0];
#pragma unroll
    for (int nd = 0; nd < 4; ++nd)
#pragma unroll
        for (int i = 0; i < 4; ++i) {
            const int row = lk * 4 + i, col = nd * 16 + l16;
            Rp[w * 1040 + row * 65 + col] = pacc[nd][i];
            Rn[w * 1040 + row * 65 + col] = nacc[nd][i];
        }
    __syncthreads();
#pragma unroll
    for (int e = tid; e < 1024; e += 256) {
        const int row = e >> 6, col = e & 63;
        const float stp = smp[0][row] + smp[1][row] + smp[2][row] + smp[3][row];
        const float stn = smn[0][row] + smn[1][row] + smn[2][row] + smn[3][row];
        const int rc = row * 65 + col;
        const float vp = (Rp[rc] + Rp[1040 + rc] + Rp[2080 + rc] + Rp[3120 + rc]) / stp;
        const float vn = -(Rn[rc] + Rn[1040 + rc] + Rn[2080 + rc] + Rn[3120 + rc]) / stn;
        const size_t o = ((size_t)(b * 512 + q0 + row)) * 768 + h * 64 + col;
        Vpb[o] = (bf16_t)vp;
        Vnb[o] = (bf16_t)vn;
    }
}

// ---------------------------------------------------------------------------
extern "C" void kernel_launch(void* const* d_in, const int* in_sizes, int n_in,
                              void* d_out, int out_size, void* d_ws, size_t ws_size,
                              hipStream_t stream) {
    const float* Q = (const float*)d_in[0];
    const float* K = (const float*)d_in[1];
    const float* V = (const float*)d_in[2];
    const float* W_q = (const float*)d_in[3];
    const float* W_k = (const float*)d_in[4];
    const float* W_v = (const float*)d_in[5];
    const float* Wpos = (const float*)d_in[6];
    const float* Wneg = (const float*)d_in[7];
    const float* W_o = (const float*)d_in[8];
    const float* W_o2 = (const float*)d_in[9];
    const float* w1 = (const float*)d_in[10];
    const float* b1 = (const float*)d_in[11];
    const float* w2 = (const float*)d_in[12];
    const float* b2 = (const float*)d_in[13];
    float* out = (float*)d_out;

    char* ws = (char*)d_ws;
    const size_t act_b = (size_t)4096 * 768 * 2;  // 6.29 MB
    bf16_t* Qb = (bf16_t*)(ws + 0 * act_b);       // later: Vpb
    bf16_t* Kb = (bf16_t*)(ws + 1 * act_b);       // later: Vnb
    bf16_t* Vb = (bf16_t*)(ws + 2 * act_b);       // later: Xb rows 0..4095
    bf16_t* vb = (bf16_t*)(ws + 3 * act_b);       // later: Xb rows 4096..8191
    bf16_t* qb = (bf16_t*)(ws + 4 * act_b);       // later: Hb rows 0..4095
    bf16_t* kb = (bf16_t*)(ws + 5 * act_b);       // later: Hb rows 4096..8191
    bf16_t* Vt = (bf16_t*)(ws + 6 * act_b);
    float* Xf = (float*)(ws + 7 * act_b);         // [8192,768] f32 = 4 act_b
    bf16_t* Wt[7];
    for (int i = 0; i < 7; ++i) Wt[i] = (bf16_t*)(ws + 11 * act_b + (size_t)i * 768 * 768 * 2);
    bf16_t* Vpb = Qb;
    bf16_t* Vnb = Kb;
    bf16_t* Xb = Vb;  // spans Vb+vb (contiguous 2*act_b)
    bf16_t* Hb = qb;  // spans qb+kb (contiguous 2*act_b)

    // 1. convert Q,K,V to bf16
    CvtPtrs cp;
    cp.src[0] = Q; cp.src[1] = K; cp.src[2] = V;
    cp.dst[0] = Qb; cp.dst[1] = Kb; cp.dst[2] = Vb;
    convert_kernel<<<dim3(1536, 3), 256, 0, stream>>>(cp, 393216);

    // 2. transpose weights
    WPtrs wp;
    wp.src[0] = W_q; wp.src[1] = W_k; wp.src[2] = W_v;
    wp.src[3] = W_o; wp.src[4] = W_o2; wp.src[5] = w1; wp.src[6] = w2;
    for (int i = 0; i < 7; ++i) wp.dst[i] = Wt[i];
    transpose_w_kernel<<<dim3(24, 24, 7), dim3(32, 8), 0, stream>>>(wp);

    // 3. q/k/v projections (batched z=3), bf16 out
    {
        GemmB g = {};
        g.A[0] = Qb; g.A[1] = Kb; g.A[2] = Vb;
        g.Bt[0] = Wt[0]; g.Bt[1] = Wt[1]; g.Bt[2] = Wt[2];
        g.Cb[0] = qb; g.Cb[1] = kb; g.Cb[2] = vb;
        gemm2<false, false, false, 1><<<dim3(12, 32, 3), 256, 0, stream>>>(g, 4096, 768, 768);
    }

    // 4. V transpose for PV
    transpose_v_kernel<<<dim3(16, 2, 96), dim3(32, 8), 0, stream>>>(vb, Vt);

    // 5. attention
    attn_kernel<<<dim3(32, 96), 256, 0, stream>>>(qb, kb, Vt, Wpos, Wneg, Vpb, Vnb);

    // 6. out projections + residual Q (dual f32+bf16 out), batched z=2
    {
        GemmB g = {};
        g.A[0] = Vpb; g.A[1] = Vnb;
        g.Bt[0] = Wt[3]; g.Bt[1] = Wt[4];
        g.Res[0] = Q; g.Res[1] = Q;
        g.Cf[0] = Xf; g.Cf[1] = Xf + (size_t)4096 * 768;
        g.Cb[0] = Xb; g.Cb[1] = Xb + (size_t)4096 * 768;
        gemm2<false, false, true, 2><<<dim3(12, 32, 2), 256, 0, stream>>>(g, 4096, 768, 768);
    }

    // 7. FFN1: relu(X @ w1 + b1), M=8192, bf16 out
    {
        GemmB g = {};
        g.A[0] = Xb;
        g.Bt[0] = Wt[5];
        g.bias = b1;
        g.Cb[0] = Hb;
        gemm2<true, true, false, 1><<<dim3(12, 64, 1), 256, 0, stream>>>(g, 8192, 768, 768);
    }

    // 8. FFN2: H @ w2 + b2 + X -> out (f32), M=8192, writes d_out directly
    {
        GemmB g = {};
        g.A[0] = Hb;
        g.Bt[0] = Wt[6];
        g.bias = b2;
        g.Res[0] = Xf;
        g.Cf[0] = out;
        gemm2<true, false, true, 0><<<dim3(12, 64, 1), 256, 0, stream>>>(g, 8192, 768, 768);
    }
}